// Round 4
// baseline (361.293 us; speedup 1.0000x reference)
//
#include <hip/hip_runtime.h>
#include <hip/hip_bf16.h>
#include <math.h>

#define C_DIM 2048
#define E_DIM 64
#define KC 32
#define NCHUNK (C_DIM / KC)   // 64
#define KC_BLK 12             // 12 chunks * 32 = 384 = OpenBLAS sgemm kc (HASWELL/ZEN Q)

typedef __attribute__((address_space(3))) float lds_f;
typedef const __attribute__((address_space(1))) float glb_f;

// ---------------------------------------------------------------------------
// numpy pairwise_sum emulation for 2048 elements, one wave:
// base case 128 elems = 8 accumulators x 16 sequential adds, combined
// ((r0+r1)+(r2+r3))+((r4+r5)+(r6+r7)); recursion = perfect binary tree ==
// the XOR-butterfly bracketing. __fmul_rn/__fadd_rn block fp-contract so the
// square is rounded separately (numpy computes x*x then sums).
// NOTE (round-3 audit): norm bit-exactness is NOT sign-critical (positive
// scalar scale); this emulation only needs ~1e-7 value accuracy, which it has
// even if the container numpy dispatches its SIMD pairwise path instead.
// ---------------------------------------------------------------------------
__device__ __forceinline__ float np_pairwise_2048(const float* __restrict__ a,
                                                  int stride, int lane) {
  const int g = lane >> 3, k = lane & 7;
  float half_tot[2];
#pragma unroll
  for (int h = 0; h < 2; ++h) {
    const int c0 = h * 1024 + g * 128 + k;
    float v = a[(size_t)c0 * stride];
    float r = __fmul_rn(v, v);
#pragma unroll
    for (int i = 1; i < 16; ++i) {
      v = a[(size_t)(c0 + 8 * i) * stride];
      r = __fadd_rn(r, __fmul_rn(v, v));
    }
    // combine 8 accumulators within the 8-lane group (numpy base-case tree)
    r = __fadd_rn(r, __shfl_xor(r, 1));
    r = __fadd_rn(r, __shfl_xor(r, 2));
    r = __fadd_rn(r, __shfl_xor(r, 4));
    // combine the 8 base-blocks of this half (pairwise recursion tree)
    r = __fadd_rn(r, __shfl_xor(r, 8));
    r = __fadd_rn(r, __shfl_xor(r, 16));
    r = __fadd_rn(r, __shfl_xor(r, 32));
    half_tot[h] = r;
  }
  return __fadd_rn(half_tot[0], half_tot[1]);  // pw(2048) = pw(1024)+pw(1024)
}

// X row norms: den[row] = max(sqrt(pairwise(x*x)), 1e-12). 4 waves/block.
__global__ __launch_bounds__(256) void xnorm_kernel(const float* __restrict__ X,
                                                    float* __restrict__ den, int N) {
  const int row = blockIdx.x * 4 + (threadIdx.x >> 6);
  const int l = threadIdx.x & 63;
  if (row >= N) return;
  const float tot = np_pairwise_2048(X + (size_t)row * C_DIM, 1, l);
  if (l == 0) den[row] = fmaxf(sqrtf(tot), 1e-12f);
}

// sim column norms + normalized transpose sT[e][c] = sim[c][e] / den_e.
// IEEE fp32 division matches numpy's elementwise divide (hipcc default
// -fhip-fp32-correctly-rounded-divide-sqrt).
__global__ __launch_bounds__(64) void simnorm_kernel(const float* __restrict__ sim,
                                                     float* __restrict__ sT) {
  const int e = blockIdx.x;
  const int l = threadIdx.x;
  const float tot = np_pairwise_2048(sim + e, E_DIM, l);
  const float den = fmaxf(sqrtf(tot), 1e-12f);  // all lanes hold tot
  for (int c = l; c < C_DIM; c += 64)
    sT[(size_t)e * C_DIM + c] = sim[(size_t)c * E_DIM + e] / den;
}

// ---------------------------------------------------------------------------
// Main kernel: block = 64 rows x 64 experts. X reg-staged (normalized in
// flight by IEEE division), sT LDS-staged via global_load_lds(16B). XOR
// swizzle (slot ^ (row>>2)&7) on source-side/read-side, linear LDS dest.
// Dot product mimics OpenBLAS sgemm: per (row,expert) single fp32
// accumulator, sequential fmaf in ascending k, kc=384 block partials folded
// into the total in block order ((p0+p1)+p2)... (matches level3.c beta=0
// pre-zero + per-block C += partial). Bit-match => zero hard-threshold flips
// vs the np reference. Row-major cblas swap does not change this bracketing.
// ---------------------------------------------------------------------------
__global__ __launch_bounds__(256) void gating_main(const float* __restrict__ X,
                                                   const float* __restrict__ denx,
                                                   const float* __restrict__ sT,
                                                   const float* __restrict__ gates,
                                                   const int* __restrict__ fbk,
                                                   float* __restrict__ out, int N) {
  __shared__ float smem[8192];  // 2 bufs x (Xn chunk 2048 + sT chunk 2048) dwords
  const int t = threadIdx.x;
  const int w = t >> 6, l = t & 63;
  const int wr = w >> 1, we = w & 1;   // wave grid: row-half x expert-half
  const int rg = l >> 3, eg = l & 7;   // lane grid: 8 row-groups x 8 expert-groups
  const size_t rowbase = (size_t)blockIdx.x * 64;
  const float* Xb = X + rowbase * C_DIM;

  // staging geometry: thread t owns 16B units u0=t, u1=t+256
  const int u0 = t, u1 = t + 256;
  const int r0 = u0 >> 3, cb0 = (u0 & 7) ^ ((r0 >> 2) & 7);
  const int r1 = u1 >> 3, cb1 = (u1 & 7) ^ ((r1 >> 2) & 7);
  const float d0 = denx[rowbase + r0];
  const float d1 = denx[rowbase + r1];

  float4 xr0, xr1;
  auto issueX = [&](int c0) {
    xr0 = *(const float4*)(Xb + (size_t)r0 * C_DIM + c0 + cb0 * 4);
    xr1 = *(const float4*)(Xb + (size_t)r1 * C_DIM + c0 + cb1 * 4);
  };
  auto issueS = [&](int buf, int c0) {
    glb_f* g0 = (glb_f*)(sT + (size_t)r0 * C_DIM + c0 + cb0 * 4);
    lds_f* s0 = (lds_f*)&smem[buf * 4096 + 2048 + u0 * 4];
    __builtin_amdgcn_global_load_lds((const __attribute__((address_space(1))) void*)g0,
                                     (__attribute__((address_space(3))) void*)s0, 16, 0, 0);
    glb_f* g1 = (glb_f*)(sT + (size_t)r1 * C_DIM + c0 + cb1 * 4);
    lds_f* s1 = (lds_f*)&smem[buf * 4096 + 2048 + u1 * 4];
    __builtin_amdgcn_global_load_lds((const __attribute__((address_space(1))) void*)g1,
                                     (__attribute__((address_space(3))) void*)s1, 16, 0, 0);
  };
  auto writeX = [&](int buf) {  // IEEE divide (matches np x/den), then ds_write_b128
    float4 a, b;
    a.x = xr0.x / d0; a.y = xr0.y / d0; a.z = xr0.z / d0; a.w = xr0.w / d0;
    b.x = xr1.x / d1; b.y = xr1.y / d1; b.z = xr1.z / d1; b.w = xr1.w / d1;
    *(float4*)&smem[buf * 4096 + u0 * 4] = a;
    *(float4*)&smem[buf * 4096 + u1 * 4] = b;
  };

  float ab[4][4], tt[4][4];
#pragma unroll
  for (int i = 0; i < 4; ++i)
#pragma unroll
    for (int j = 0; j < 4; ++j) ab[i][j] = 0.f;

  // prologue: stage chunk 0
  issueX(0);
  issueS(0, 0);
  writeX(0);  // compiler waits xr before use
  asm volatile("s_waitcnt vmcnt(0) lgkmcnt(0)" ::: "memory");
  __builtin_amdgcn_s_barrier();
  asm volatile("" ::: "memory");

  for (int ch = 0; ch < NCHUNK; ++ch) {
    const int buf = ch & 1;
    if (ch + 1 < NCHUNK) {
      issueX((ch + 1) * KC);        // in flight during compute
      issueS(buf ^ 1, (ch + 1) * KC);
    }
    if (ch && (ch % KC_BLK) == 0) {  // kc-block boundary: fold partial into C
#pragma unroll
      for (int i = 0; i < 4; ++i)
#pragma unroll
        for (int j = 0; j < 4; ++j) {
          if (ch == KC_BLK) tt[i][j] = ab[i][j];
          else tt[i][j] = __fadd_rn(tt[i][j], ab[i][j]);
          ab[i][j] = 0.f;
        }
    }

    const int xb = buf * 4096;
    const int sb = xb + 2048;
#pragma unroll
    for (int u = 0; u < 8; ++u) {
      float4 xv[4], sv[4];
#pragma unroll
      for (int i = 0; i < 4; ++i) {
        const int row = wr * 32 + rg * 4 + i;   // (row>>2)&7 == rg
        xv[i] = *(const float4*)&smem[xb + row * 32 + (u ^ rg) * 4];
      }
#pragma unroll
      for (int j = 0; j < 4; ++j) {
        const int er = we * 32 + eg * 4 + j;    // (er>>2)&7 == eg
        sv[j] = *(const float4*)&smem[sb + er * 32 + (u ^ eg) * 4];
      }
#pragma unroll
      for (int i = 0; i < 4; ++i)
#pragma unroll
        for (int j = 0; j < 4; ++j) {           // strict ascending-k fmaf chain
          float a = ab[i][j];
          a = fmaf(xv[i].x, sv[j].x, a);
          a = fmaf(xv[i].y, sv[j].y, a);
          a = fmaf(xv[i].z, sv[j].z, a);
          a = fmaf(xv[i].w, sv[j].w, a);
          ab[i][j] = a;
        }
    }
    asm volatile("" ::: "memory");
    if (ch + 1 < NCHUNK) writeX(buf ^ 1);
    asm volatile("s_waitcnt vmcnt(0) lgkmcnt(0)" ::: "memory");
    __builtin_amdgcn_s_barrier();
    asm volatile("" ::: "memory");
  }
#pragma unroll
  for (int i = 0; i < 4; ++i)
#pragma unroll
    for (int j = 0; j < 4; ++j) tt[i][j] = __fadd_rn(tt[i][j], ab[i][j]);  // tail 128

  // ---- epilogue: logits -> LDS transpose, then per-row wave ops ----
  float* lg = smem;  // [64][66], stride 66 => conflict-free row reads
#pragma unroll
  for (int i = 0; i < 4; ++i) {
    const int row = wr * 32 + rg * 4 + i;
#pragma unroll
    for (int j = 0; j < 4; ++j) lg[row * 66 + we * 32 + eg * 4 + j] = tt[i][j];
  }
  __syncthreads();

  const int k = fbk[0];
  const float gate = gates[l];
  const size_t NE = (size_t)N * E_DIM;

  for (int rr = 0; rr < 16; ++rr) {
    const int row = w * 16 + rr;  // each wave owns 16 rows; lane = expert
    const float logit = __fadd_rn(lg[row * 66 + l], -gate);  // matmul - gates
    const float gated = fmaxf(logit, 0.f);
    const bool act = logit > 0.f;
    const unsigned long long bal = __ballot(act);
    const bool inactive = (bal == 0ull);

    // top-k of raw logits (tie -> lowest index, matching lax.top_k)
    float cur = logit;
    bool fb = false;
    for (int tk = 0; tk < k; ++tk) {
      float v = cur;
      int idx = l;
#pragma unroll
      for (int off = 32; off >= 1; off >>= 1) {
        const float ov = __shfl_xor(v, off);
        const int oi = __shfl_xor(idx, off);
        if (ov > v || (ov == v && oi < idx)) { v = ov; idx = oi; }
      }
      if (l == idx) { cur = -INFINITY; fb = true; }
    }

    const float mask = inactive ? (fb ? 1.f : 0.f) : (act ? 1.f : 0.f);
    const float masked = (mask > 0.f) ? gated : -INFINITY;
    float m = masked;
#pragma unroll
    for (int off = 32; off >= 1; off >>= 1) m = fmaxf(m, __shfl_xor(m, off));
    const float p = (mask > 0.f) ? expf(masked - m) : 0.f;
    float s = p;
#pragma unroll
    for (int off = 32; off >= 1; off >>= 1) s += __shfl_xor(s, off);
    const float wgt = p / s;

    const size_t gr = rowbase + row;
    out[gr * E_DIM + l] = wgt;             // routing_weights
    out[NE + gr * E_DIM + l] = logit;      // logits
    out[2 * NE + gr * E_DIM + l] = mask;   // activation_mask
  }
}

extern "C" void kernel_launch(void* const* d_in, const int* in_sizes, int n_in,
                              void* d_out, int out_size, void* d_ws, size_t ws_size,
                              hipStream_t stream) {
  (void)n_in; (void)out_size; (void)ws_size;
  const float* X = (const float*)d_in[0];
  const float* sim = (const float*)d_in[1];
  const float* gates = (const float*)d_in[2];
  const int* fbk = (const int*)d_in[3];
  float* out = (float*)d_out;
  float* den = (float*)d_ws;                       // 16384 fp32 = 64 KB
  float* sT = (float*)d_ws + 16384;                // 64*2048 fp32 = 512 KB
  const int N = in_sizes[0] / C_DIM;               // 16384

  hipLaunchKernelGGL(xnorm_kernel, dim3(N / 4), dim3(256), 0, stream, X, den, N);
  hipLaunchKernelGGL(simnorm_kernel, dim3(E_DIM), dim3(64), 0, stream, sim, sT);
  hipLaunchKernelGGL(gating_main, dim3(N / 64), dim3(256), 0, stream, X, den, sT, gates, fbk, out, N);
}